// Round 12
// baseline (132.245 us; speedup 1.0000x reference)
//
#include <hip/hip_runtime.h>
#include <hip/hip_bf16.h>

typedef __attribute__((ext_vector_type(8))) __bf16 bf16x8;
typedef __attribute__((ext_vector_type(4))) __bf16 bf16x4;
typedef __attribute__((ext_vector_type(4))) float f32x4;
typedef __attribute__((ext_vector_type(16))) float f32x16;

#define DIM 2048
#define SEQ 2048
#define NH 32
#define NKV 8
#define HD 64
#define QKVD 3072          // 2048 Q | 512 K | 512 V packed columns
#define KOFF 2048
#define VOFF 2560
#define KVDIM 512

// async global->LDS, 16B per lane, wave-uniform LDS base (HW: base + lane*16)
__device__ __forceinline__ void gld16(const __bf16* g, __bf16* l) {
    __builtin_amdgcn_global_load_lds(
        (const __attribute__((address_space(1))) void*)g,
        (__attribute__((address_space(3))) void*)l, 16, 0, 0);
}

// ---------------- fused fp32 -> bf16 convert, all 5 tensors ----------------
__global__ __launch_bounds__(256) void cvt_all(const float* __restrict__ x,
                                               const float* __restrict__ wq,
                                               const float* __restrict__ wk,
                                               const float* __restrict__ wv,
                                               const float* __restrict__ wo,
                                               __bf16* __restrict__ xb,
                                               __bf16* __restrict__ wqkvb,
                                               __bf16* __restrict__ wob) {
    const int i = blockIdx.x * blockDim.x + threadIdx.x;
    const int NX = SEQ * DIM / 4;          // 1048576
    const int NW = DIM * DIM / 4;          // 1048576
    const int NKV4 = KVDIM * DIM / 4;      // 262144
    const float* src; __bf16* dst; int off;
    if (i < NX)                        { src = x;  dst = xb;    off = i; }
    else if (i < NX + NW)              { src = wq; dst = wqkvb; off = i - NX; }
    else if (i < NX + NW + NKV4)       { src = wk; dst = wqkvb + (size_t)KOFF * DIM; off = i - NX - NW; }
    else if (i < NX + NW + 2 * NKV4)   { src = wv; dst = wqkvb + (size_t)VOFF * DIM; off = i - NX - NW - NKV4; }
    else                               { src = wo; dst = wob;   off = i - NX - NW - 2 * NKV4; }
    float4 v = reinterpret_cast<const float4*>(src)[off];
    bf16x4 o;
    o[0] = (__bf16)v.x; o[1] = (__bf16)v.y; o[2] = (__bf16)v.z; o[3] = (__bf16)v.w;
    reinterpret_cast<bf16x4*>(dst)[off] = o;
}

// ---------------- TN GEMM: 128x64 tile, 8 waves x (32x32), BK=64, dbuf ------
// (unchanged round-11 winner)
template <typename OutT, bool ROPE>
__global__ __launch_bounds__(512, 6) void gemm_tn(const __bf16* __restrict__ A,
                                                  const __bf16* __restrict__ B,
                                                  OutT* __restrict__ C,
                                                  int M, int N, int K,
                                                  float scale, int scaleNlim,
                                                  const float* __restrict__ fc,
                                                  const float* __restrict__ fs,
                                                  __bf16* __restrict__ VTout) {
    __shared__ __align__(16) __bf16 As[2][2][128 * 32];   // 32 KB
    __shared__ __align__(16) __bf16 Bs[2][2][64 * 32];    // 16 KB
    const int tid = threadIdx.x;
    const int lane = tid & 63;
    const int w = tid >> 6;               // 0..7
    const int l15 = lane & 15, lhi = lane >> 4;
    const int mb = blockIdx.y * 128;
    const int nb = blockIdx.x * 64;
    const int wm = (w >> 1) * 32, wn = (w & 1) * 32;

    const int srow = lane >> 2, scol = (lane & 3) * 8;
    const __bf16* gA = A + (size_t)(mb + w * 16 + srow) * K + scol;
    const __bf16* gB = B + (size_t)(nb + (w & 3) * 16 + srow) * K + scol;
    const int bsub = w >> 2;

    auto stage = [&](int kk, int buf) {
#pragma unroll
        for (int s = 0; s < 2; ++s)
            gld16(gA + kk + s * 32, As[buf][s] + w * 512);
        gld16(gB + kk + bsub * 32, Bs[buf][bsub] + (w & 3) * 512);
    };

    stage(0, 0);
    __syncthreads();

    f32x4 acc[2][2] = {};
    int cur = 0;
    for (int kk = 0; kk < K; kk += 64, cur ^= 1) {
        if (kk + 64 < K) stage(kk + 64, cur ^ 1);
#pragma unroll
        for (int s = 0; s < 2; ++s) {
            bf16x8 a[2], b[2];
#pragma unroll
            for (int i = 0; i < 2; ++i)
                a[i] = *reinterpret_cast<const bf16x8*>(&As[cur][s][(wm + i * 16 + l15) * 32 + lhi * 8]);
#pragma unroll
            for (int j = 0; j < 2; ++j)
                b[j] = *reinterpret_cast<const bf16x8*>(&Bs[cur][s][(wn + j * 16 + l15) * 32 + lhi * 8]);
#pragma unroll
            for (int i = 0; i < 2; ++i)
#pragma unroll
                for (int j = 0; j < 2; ++j)
                    acc[i][j] = __builtin_amdgcn_mfma_f32_16x16x32_bf16(a[i], b[j], acc[i][j], 0, 0, 0);
        }
        __syncthreads();
    }

    const bool toVT = ROPE && (VTout != nullptr) && (nb >= VOFF);
    if (toVT) {
#pragma unroll
        for (int i = 0; i < 2; ++i)
#pragma unroll
            for (int j = 0; j < 2; ++j) {
                bf16x4 pv;
#pragma unroll
                for (int r = 0; r < 4; ++r) pv[r] = (__bf16)acc[i][j][r];
                const int colv = nb - VOFF + wn + j * 16 + l15;
                const int row0 = mb + wm + i * 16 + lhi * 4;
                *reinterpret_cast<bf16x4*>(VTout + (size_t)colv * M + row0) = pv;
            }
    } else {
        const float sc = (nb < scaleNlim) ? scale : 1.0f;
        const bool doRope = ROPE && (nb < VOFF);
#pragma unroll
        for (int i = 0; i < 2; ++i)
#pragma unroll
            for (int j = 0; j < 2; ++j)
#pragma unroll
                for (int r = 0; r < 4; ++r) {
                    float v = acc[i][j][r] * sc;
                    if (doRope) {
                        const int col = nb + wn + j * 16 + l15;
                        const int row = mb + wm + i * 16 + lhi * 4 + r;
                        const float vp = __shfl_xor(v, 1);
                        const int fi = (col & 63) >> 1;
                        const float cc = fc[row * 32 + fi];
                        const float ss = fs[row * 32 + fi];
                        v = (col & 1) ? (vp * ss + v * cc) : (v * cc - vp * ss);
                    }
                    C[(size_t)(mb + wm + i * 16 + lhi * 4 + r) * N + nb + wn + j * 16 + l15] = (OutT)v;
                }
    }
}

// ---------------- Flash attention: 32x32 MFMA, (q-half x kv-half) waves -----
// Block = 64 q rows, 4 waves: wave w -> q-half (w&1), kv-half (w>>1).
// Each wave: 1x 32x32 S^T tile (4 MFMA) + partial PV over its kv-half
// (4 MFMA), independent online-softmax state, flash-merge at epilogue.
// LDS 40 KB -> 4 blocks/CU; grid 1024 with CU-sum-balanced qt map.
__global__ __launch_bounds__(256, 4) void attn_kernel(const __bf16* __restrict__ QKV,
                                                      const __bf16* __restrict__ VT,
                                                      __bf16* __restrict__ Y) {
    const int bx = blockIdx.x;
    const int g = bx >> 8;                // 0..3
    const int a = (bx >> 5) & 7;          // 0..7
    const int h = bx & 31;
    const int qt = (g == 0) ? 31 - a : (g == 1) ? a : (g == 2) ? 23 - a : 8 + a;
    const int kvh = h >> 2;
    const int tid = threadIdx.x;
    const int lane = tid & 63;
    const int w = tid >> 6;
    const int l31 = lane & 31;
    const int lhi2 = lane >> 5;           // 0/1: k-group within fragments
    const int qhalf = w & 1;
    const int kvhalf = w >> 1;

    __shared__ __align__(16) unsigned char smem[40960];
    __bf16* Kl = (__bf16*)smem;                    // [2][64*64] 16 KB, d-slot XOR-swz
    __bf16* Vl = (__bf16*)(smem + 16384);          // [2][64*64] 16 KB, kv-slot XOR-swz
    __bf16* Pl = (__bf16*)(smem + 32768);          // [4][32*32]  8 KB, slot^(q&3) swz

    const __bf16* Qp = QKV + h * HD;
    const __bf16* Kp = QKV + KOFF + kvh * HD;
    const __bf16* Vth = VT + (size_t)(kvh * HD) * SEQ;

    // staging lane map (unchanged): row-in-chunk sr=lane>>3, slot (l&7)^sr
    const int sr = lane >> 3;
    const int ksc = ((lane & 7) ^ sr) * 8;

    auto stage = [&](int jt, int buf) {
        const int kvb = jt * 64;
#pragma unroll
        for (int c = 0; c < 2; ++c) {
            const int row = w * 16 + c * 8;
            gld16(Kp + (size_t)(kvb + row + sr) * QKVD + ksc, Kl + buf * 4096 + row * 64);
            gld16(Vth + (size_t)(row + sr) * SEQ + kvb + ksc, Vl + buf * 4096 + row * 64);
        }
    };

    const int qb = qt * 64;
    const int qrow = qb + qhalf * 32 + l31;   // lane's q (S^T col = l&31)

    // Q fragments (B-operand): col=q=l31, k = c*16 + lhi2*8 (+0..7)
    const __bf16* qptr = Qp + (size_t)qrow * QKVD;
    bf16x8 qf[4];
#pragma unroll
    for (int c = 0; c < 4; ++c)
        qf[c] = *reinterpret_cast<const bf16x8*>(qptr + c * 16 + lhi2 * 8);

    f32x16 o0 = {}, o1 = {};              // O partial: d-tiles 0 / 1
    float mrun = -1e30f;
    float lpart = 0.f;

    const int pswz = l31 & 3;             // P 16B-slot XOR key
    const int rsw7 = l31 & 7;             // K/V read row-key

    stage(0, 0);
    __syncthreads();

    int cur = 0;
    for (int j = 0; j <= qt; ++j, cur ^= 1) {
        const bool pre = (j < qt);
        if (pre) stage(j + 1, cur ^ 1);

        // wave 2 (q-lo, kv-hi) is fully masked on the diagonal tile: skip
        if (!(j == qt && kvhalf == 1 && qhalf == 0)) {
            // ---- S^T(32kv x 32q) = K(32kv x 64d) . Q^T : 4 MFMA over d
            f32x16 sacc = {};
            const __bf16* Kb = Kl + cur * 4096 + (kvhalf * 32 + l31) * 64;
            __builtin_amdgcn_s_setprio(1);
#pragma unroll
            for (int c = 0; c < 4; ++c) {
                bf16x8 kf = *reinterpret_cast<const bf16x8*>(
                    Kb + (((c * 2 + lhi2) ^ rsw7) * 8));
                sacc = __builtin_amdgcn_mfma_f32_32x32x16_bf16(kf, qf[c], sacc, 0, 0, 0);
            }
            __builtin_amdgcn_s_setprio(0);

            // ---- causal mask (diagonal tile, waves with kvhalf==qhalf)
            if (j == qt && kvhalf == qhalf) {
#pragma unroll
                for (int r = 0; r < 16; ++r) {
                    const int kvl = (r & 3) + 8 * (r >> 2) + 4 * lhi2;
                    if (kvl > l31) sacc[r] = -1e30f;
                }
            }

            // ---- per-lane partial max; cross-lane only on (rare) rescale
            float pm = sacc[0];
#pragma unroll
            for (int r = 1; r < 16; ++r) pm = fmaxf(pm, sacc[r]);

            if (!__all(pm - mrun <= 8.0f)) {          // T13 defer-max
                const float full = fmaxf(pm, __shfl_xor(pm, 32));
                const float mn = fmaxf(mrun, full);
                const float aa = exp2f(mrun - mn);
                mrun = mn;
                lpart *= aa;
#pragma unroll
                for (int r = 0; r < 16; ++r) {
                    const int qi = (r & 3) + 8 * (r >> 2) + 4 * lhi2;
                    const float ar = __shfl(aa, qi);
                    o0[r] *= ar; o1[r] *= ar;
                }
            }

            // ---- P = exp2(S - m), pack to Pl (row q, 16B-slot g ^ (q&3))
            __bf16* Pw = Pl + w * 1024 + l31 * 32;
            float ps = 0.f;
#pragma unroll
            for (int gg = 0; gg < 4; ++gg) {
                bf16x4 pk;
#pragma unroll
                for (int rr = 0; rr < 4; ++rr) {
                    const float pv = exp2f(sacc[gg * 4 + rr] - mrun);
                    ps += pv;
                    pk[rr] = (__bf16)pv;
                }
                *reinterpret_cast<bf16x4*>(Pw + ((gg ^ pswz) * 8) + lhi2 * 4) = pk;
            }
            lpart += ps;

            // ---- O += P V (partial over this wave's kv-half)
            bf16x8 pf[2];
#pragma unroll
            for (int c = 0; c < 2; ++c)
                pf[c] = *reinterpret_cast<const bf16x8*>(
                    Pw + (((c * 2 + lhi2) ^ pswz) * 8));
            const __bf16* Vb0 = Vl + cur * 4096 + l31 * 64;          // d-tile 0
            const __bf16* Vb1 = Vl + cur * 4096 + (32 + l31) * 64;   // d-tile 1
            __builtin_amdgcn_s_setprio(1);
#pragma unroll
            for (int c = 0; c < 2; ++c) {
                const int s = kvhalf * 4 + c * 2 + lhi2;
                bf16x8 vf0 = *reinterpret_cast<const bf16x8*>(Vb0 + ((s ^ rsw7) * 8));
                bf16x8 vf1 = *reinterpret_cast<const bf16x8*>(Vb1 + ((s ^ rsw7) * 8));
                o0 = __builtin_amdgcn_mfma_f32_32x32x16_bf16(pf[c], vf0, o0, 0, 0, 0);
                o1 = __builtin_amdgcn_mfma_f32_32x32x16_bf16(pf[c], vf1, o1, 0, 0, 0);
            }
            __builtin_amdgcn_s_setprio(0);
        }

        __syncthreads();   // drains gld16 prefetch + guards buffer reuse
    }

    // ---- epilogue: flash-merge the two kv-half partials per q-half --------
    const float ls = lpart + __shfl_xor(lpart, 32);   // per-q, pair-uniform
    float* ex = (float*)smem;                          // 16 KB O-exchange
    float* exm = (float*)(smem + 32768);               // m/ls exchange (Pl area)

    if (kvhalf == 1) {
        float* dst = ex + qhalf * 2048 + lane * 32;
#pragma unroll
        for (int r = 0; r < 16; ++r) { dst[r] = o0[r]; dst[16 + r] = o1[r]; }
        if (lane < 32) {
            exm[qhalf * 64 + l31] = mrun;
            exm[qhalf * 64 + 32 + l31] = ls;
        }
    }
    __syncthreads();
    if (kvhalf == 0) {
        const float mo = exm[qhalf * 64 + l31];
        const float lso = exm[qhalf * 64 + 32 + l31];
        const float mn = fmaxf(mrun, mo);
        const float a0 = exp2f(mrun - mn);
        const float a1 = exp2f(mo - mn);
        const float lst = ls * a0 + lso * a1;
        const float* src = ex + qhalf * 2048 + lane * 32;
#pragma unroll
        for (int r = 0; r < 16; ++r) {
            const int qi = (r & 3) + 8 * (r >> 2) + 4 * lhi2;
            const float A0 = __shfl(a0, qi);
            const float A1 = __shfl(a1, qi);
            const float L = __shfl(lst, qi);
            const float v0 = (o0[r] * A0 + src[r] * A1) / L;
            const float v1 = (o1[r] * A0 + src[16 + r] * A1) / L;
            const size_t qg = (size_t)(qb + qhalf * 32 + qi);
            Y[qg * DIM + h * HD + l31] = (__bf16)v0;
            Y[qg * DIM + h * HD + 32 + l31] = (__bf16)v1;
        }
    }
}

extern "C" void kernel_launch(void* const* d_in, const int* in_sizes, int n_in,
                              void* d_out, int out_size, void* d_ws, size_t ws_size,
                              hipStream_t stream) {
    const float* x    = (const float*)d_in[0];
    const float* fcos = (const float*)d_in[1];
    const float* fsin = (const float*)d_in[2];
    const float* wq   = (const float*)d_in[3];
    const float* wk   = (const float*)d_in[4];
    const float* wv   = (const float*)d_in[5];
    const float* wo   = (const float*)d_in[6];
    float* out = (float*)d_out;

    __bf16* xb    = (__bf16*)d_ws;                       // [2048][2048]
    __bf16* wqkvb = xb + (size_t)SEQ * DIM;              // [3072][2048]
    __bf16* wob   = wqkvb + (size_t)QKVD * DIM;          // [2048][2048]
    __bf16* QKVb  = wob + (size_t)DIM * DIM;             // [2048][3072]
    __bf16* Yb    = QKVb + (size_t)SEQ * QKVD;           // [2048][2048]
    __bf16* VTb   = Yb + (size_t)SEQ * DIM;              // [512][2048]

    const int ncvt = (SEQ * DIM / 4) + 2 * (DIM * DIM / 4) + 2 * (KVDIM * DIM / 4);
    cvt_all<<<ncvt / 256, 256, 0, stream>>>(x, wq, wk, wv, wo, xb, wqkvb, wob);

    // fused QKV projection + RoPE + V-transpose; Q pre-scaled by 0.125*log2(e)
    gemm_tn<__bf16, true><<<dim3(QKVD / 64, SEQ / 128), 512, 0, stream>>>(
        xb, wqkvb, QKVb, SEQ, QKVD, DIM, 0.125f * 1.4426950408889634f, KOFF,
        fcos, fsin, VTb);

    attn_kernel<<<dim3(1024), 256, 0, stream>>>(QKVb, VTb, Yb);

    gemm_tn<float, false><<<dim3(DIM / 64, SEQ / 128), 512, 0, stream>>>(
        Yb, wob, out, SEQ, DIM, DIM, 1.0f, 0, nullptr, nullptr, nullptr);
}